// Round 1
// 646.899 us; speedup vs baseline: 1.1125x; 1.1125x over previous
//
#include <hip/hip_runtime.h>
#include <hip/hip_bf16.h>
#include <math.h>

typedef __bf16 bf16x8 __attribute__((ext_vector_type(8)));
typedef float f32x4 __attribute__((ext_vector_type(4)));

#define GLOBAL_LOAD_LDS16(gptr, lptr) \
  __builtin_amdgcn_global_load_lds((const __attribute__((address_space(1))) void*)(gptr), \
                                   (__attribute__((address_space(3))) void*)(lptr), 16, 0, 0)

// LDS xor-swizzle: element (row r, 16B-chunk q of 4) lives at physical chunk
// (r>>1)*8 + ((((r&1)<<2)|q) ^ ((r>>1)&7)). ds_read_b128 then spreads 16 lanes
// over all 8 bank-groups (2-way = free) instead of 8-way conflicts.
__device__ __forceinline__ int swz_off(int r, int quad) {
  return ((r >> 1) << 6) + (((((r & 1) << 2) | quad) ^ ((r >> 1) & 7)) << 3);
}

// ---------------------------------------------------------------------------
// bf16 GEMM: C[M,N] = A[M,K] @ BT[N,K]^T. 128x128 tile, BK=32, 16x16x32 MFMA.
// K = per-block K-slice length, Ktot = full K (row stride).
// MODE 0: GEMM1a split epilogue (xBC bf16 stride 4352 | dt fp32 via out2)
// MODE 2: z-GEMM + gate: g = y*silu(z)*nw in-place into yio; ssum[t] += yf^2
// MODE 3: final GEMM, rows scaled by rsqrt(ssum/4096+eps), plain fp32 store
// ---------------------------------------------------------------------------
template<int MODE>
__global__ __launch_bounds__(256, 3)
void gemm_kernel(const __bf16* __restrict__ A, const __bf16* __restrict__ BT,
                 int M, int N, int K, int Ktot,
                 __bf16* __restrict__ out0, float* __restrict__ out2,
                 __bf16* yio, float* __restrict__ ssum,
                 const float* __restrict__ nwp)
{
  __shared__ __align__(16) __bf16 As[128 * 32];
  __shared__ __align__(16) __bf16 Bs[128 * 32];
  const int tid  = threadIdx.x;
  const int wave = tid >> 6, lane = tid & 63;
  const int quad = lane >> 4, l16 = lane & 15;
  const int mBase = blockIdx.y * 128;
  const int nBase = blockIdx.x * 128;
  const int wm = (wave & 1) * 64;
  const int wn = (wave >> 1) * 64;
  const int kb = (MODE == 3) ? blockIdx.z : 0;
  const int kStart = kb * K, kEnd = kb * K + K;

  f32x4 acc[4][4] = {};

  for (int k0 = kStart; k0 < kEnd; k0 += 32) {
    __syncthreads();
    for (int rd = 0; rd < 2; ++rd) {
      int p = tid + rd * 256;                 // physical 16B-chunk 0..511
      int rp = p >> 3, wi = p & 7;
      int sp = wi ^ (rp & 7);                 // logical chunk this slot holds
      int srow = rp * 2 + (sp >> 2);
      int sc8 = (sp & 3) * 8;
      const __bf16* gpA = A + (size_t)(mBase + srow) * Ktot + k0 + sc8;
      GLOBAL_LOAD_LDS16(gpA, As + rd * 2048 + wave * 512);
      int gr = nBase + srow; if (gr >= N) gr = N - 1;   // clamp (epilogue masks)
      const __bf16* gpB = BT + (size_t)gr * Ktot + k0 + sc8;
      GLOBAL_LOAD_LDS16(gpB, Bs + rd * 2048 + wave * 512);
    }
    __syncthreads();
    bf16x8 af[4], bfr[4];
    for (int i = 0; i < 4; ++i)
      af[i] = *(const bf16x8*)(As + swz_off(wm + i * 16 + l16, quad));
    for (int j = 0; j < 4; ++j)
      bfr[j] = *(const bf16x8*)(Bs + swz_off(wn + j * 16 + l16, quad));
    for (int i = 0; i < 4; ++i)
      for (int j = 0; j < 4; ++j)
        acc[i][j] = __builtin_amdgcn_mfma_f32_16x16x32_bf16(af[i], bfr[j], acc[i][j], 0, 0, 0);
  }

  // epilogue: C/D layout col = lane&15, row = quad*4 + r
  if (MODE == 2) {
    for (int i = 0; i < 4; ++i)
      for (int r = 0; r < 4; ++r) {
        int row = mBase + wm + i * 16 + quad * 4 + r;
        float sq = 0.f;
        for (int j = 0; j < 4; ++j) {
          int col = nBase + wn + j * 16 + l16;
          float v = acc[i][j][r];
          size_t idx = (size_t)row * 4096 + col;
          float y0 = (float)yio[idx];
          float zg = v / (1.f + expf(-v));    // silu(z)
          float yf = y0 * zg;
          yio[idx] = (__bf16)(yf * nwp[col]);
          sq += yf * yf;
        }
        for (int m = 1; m < 16; m <<= 1) sq += __shfl_xor(sq, m, 64);
        if (l16 == 0) atomicAdd(&ssum[row], sq);
      }
  } else if (MODE == 3) {
    // row scale hoisted: 16 rows per thread, one rsqrt each
    float rs[4][4];
    for (int i = 0; i < 4; ++i)
      for (int r = 0; r < 4; ++r) {
        int row = mBase + wm + i * 16 + quad * 4 + r;
        rs[i][r] = rsqrtf(ssum[row] / 4096.f + 1e-5f);
      }
    for (int i = 0; i < 4; ++i) {
      int rowl = wm + i * 16 + quad * 4;
      for (int j = 0; j < 4; ++j) {
        int col = nBase + wn + j * 16 + l16;
        for (int r = 0; r < 4; ++r) {
          int row = mBase + rowl + r;
          float o = acc[i][j][r] * rs[i][r];
          o = (o == o && fabsf(o) < 1e30f) ? o : 0.f;
          out2[(size_t)row * N + col] = o;
        }
      }
    }
  } else {
    for (int i = 0; i < 4; ++i) {
      int rowl = wm + i * 16 + quad * 4;
      for (int j = 0; j < 4; ++j) {
        int col = nBase + wn + j * 16 + l16;
        for (int r = 0; r < 4; ++r) {
          float v = acc[i][j][r];
          int row = mBase + rowl + r;
          if (col < 4352)       out0[(size_t)row * 4352 + col]        = (__bf16)v;
          else if (col < 4416)  out2[(size_t)row * 64 + (col - 4352)] = v;
        }
      }
    }
  }
}

// ---------------------------------------------------------------------------
// fp32 -> bf16 cast (coalesced, 8 elems/thread)
// ---------------------------------------------------------------------------
__global__ __launch_bounds__(256)
void cast_kernel(const float* __restrict__ in, __bf16* __restrict__ out)
{
  size_t g = ((size_t)blockIdx.x * 256 + threadIdx.x) * 8;
  for (int j = 0; j < 8; ++j) out[g + j] = (__bf16)in[g + j];
}

// ---------------------------------------------------------------------------
// fp32 transpose+cast with input column offset: out[c][r] = (bf16)in[r][col0+c].
// ---------------------------------------------------------------------------
__global__ __launch_bounds__(256)
void transpose_kernel(const float* __restrict__ in, __bf16* __restrict__ out,
                      int R, int C, int col0)
{
  __shared__ __bf16 tile[64][72];
  const int tid = threadIdx.x;
  const int r0 = blockIdx.y * 64, c0 = blockIdx.x * 64;
  const int tr = tid >> 3, tc = (tid & 7) * 8;   // tr 0..31
  for (int hh = 0; hh < 2; ++hh) {
    const float* gp = in + (size_t)(r0 + tr + hh * 32) * C + col0 + c0 + tc;
    for (int j = 0; j < 8; ++j) tile[tr + hh * 32][tc + j] = (__bf16)gp[j];
  }
  __syncthreads();
  for (int hh = 0; hh < 2; ++hh) {
    __bf16* op = out + (size_t)(c0 + tr + hh * 32) * R + r0 + tc;
    for (int j = 0; j < 8; ++j) op[j] = tile[tc + j][tr + hh * 32];
  }
}

// ---------------------------------------------------------------------------
// causal conv1d (K=4) + bias + SiLU over [4096, 4352]; routes x / B / C + BT.
// ---------------------------------------------------------------------------
__global__ __launch_bounds__(256)
void conv_silu_kernel(const __bf16* __restrict__ xBCraw, const float* __restrict__ conv_w,
                      const float* __restrict__ conv_b,
                      __bf16* __restrict__ xconv, __bf16* __restrict__ Bmat,
                      __bf16* __restrict__ Cmat, __bf16* __restrict__ BTr)
{
  int g = blockIdx.x * 256 + threadIdx.x;       // 4096 * 544 threads
  int t = g / 544;
  int c = (g % 544) * 8;
  float acc[8];
  for (int j = 0; j < 8; ++j) acc[j] = conv_b[c + j];
  for (int k = 0; k < 4; ++k) {
    int ts = t + k - 3;
    if (ts >= 0) {
      const __bf16* xp = xBCraw + (size_t)ts * 4352 + c;
      const float*  wp = conv_w + (size_t)k * 4352 + c;
      for (int j = 0; j < 8; ++j) acc[j] += (float)xp[j] * wp[j];
    }
  }
  for (int j = 0; j < 8; ++j) { float v = acc[j]; acc[j] = v / (1.f + expf(-v)); }
  if (c < 4096) {
    __bf16* op = xconv + (size_t)t * 4096 + c;
    for (int j = 0; j < 8; ++j) op[j] = (__bf16)acc[j];
  } else if (c < 4224) {
    int n = c - 4096;
    for (int j = 0; j < 8; ++j) {
      Bmat[(size_t)t * 128 + n + j] = (__bf16)acc[j];
      BTr[(size_t)(n + j) * 4096 + t] = (__bf16)acc[j];
    }
  } else {
    int n = c - 4224;
    for (int j = 0; j < 8; ++j) Cmat[(size_t)t * 128 + n + j] = (__bf16)acc[j];
  }
}

// ---------------------------------------------------------------------------
// dt = clip(softplus(dtraw + bias)); dA = dt*A; within-chunk inclusive cumsum.
// ---------------------------------------------------------------------------
__global__ __launch_bounds__(256)
void dt_cumsum_kernel(const float* __restrict__ dtraw, const float* __restrict__ dt_bias,
                      const float* __restrict__ A_log, float* __restrict__ dtp,
                      float* __restrict__ csbuf)
{
  int h = blockIdx.x, cch = blockIdx.y, i = threadIdx.x;
  int t = cch * 256 + i;
  float x = dtraw[(size_t)t * 64 + h] + dt_bias[h];
  float sp = (x > 20.f) ? x : log1pf(expf(x));
  sp = fminf(fmaxf(sp, 0.f), 100.f);
  dtp[(size_t)t * 64 + h] = sp;
  float Ah = -expf(A_log[h]);
  __shared__ float s[256];
  s[i] = sp * Ah;
  __syncthreads();
  for (int off = 1; off < 256; off <<= 1) {
    float add = (i >= off) ? s[i - off] : 0.f;
    __syncthreads();
    s[i] += add;
    __syncthreads();
  }
  csbuf[(size_t)h * 4096 + t] = s[i];
}

// ---------------------------------------------------------------------------
// xdtT[hp][t] = xconv[t][hp] * dtp[t][h]
// ---------------------------------------------------------------------------
__global__ __launch_bounds__(256)
void xdtT_kernel(const __bf16* __restrict__ xconv, const float* __restrict__ dtp,
                 __bf16* __restrict__ xdtT)
{
  __shared__ __bf16 tile[64][72];
  const int tid = threadIdx.x;
  const int t0 = blockIdx.y * 64, c0 = blockIdx.x * 64;
  const int tr = tid >> 3, tc = (tid & 7) * 8;
  const int h = (c0 + tc) >> 6;
  for (int hh = 0; hh < 2; ++hh) {
    int t = t0 + tr + hh * 32;
    float ds = dtp[(size_t)t * 64 + h];
    const __bf16* gp = xconv + (size_t)t * 4096 + c0 + tc;
    for (int j = 0; j < 8; ++j) tile[tr + hh * 32][tc + j] = (__bf16)((float)gp[j] * ds);
  }
  __syncthreads();
  for (int hh = 0; hh < 2; ++hh) {
    __bf16* op = xdtT + (size_t)(c0 + tr + hh * 32) * 4096 + t0 + tc;
    for (int j = 0; j < 8; ++j) op[j] = tile[tc + j][tr + hh * 32];
  }
}

// ---------------------------------------------------------------------------
// raw chunk scores[c][l][s] = sum_n C[l,n] B[s,n]
// ---------------------------------------------------------------------------
__global__ __launch_bounds__(256)
void scores_kernel(const __bf16* __restrict__ Cmat, const __bf16* __restrict__ Bmat,
                   __bf16* __restrict__ scores)
{
  const int c = blockIdx.x;
  const int lb = blockIdx.y * 128, sb = blockIdx.z * 128;
  const int tid = threadIdx.x, wave = tid >> 6, lane = tid & 63;
  const int quad = lane >> 4, l16 = lane & 15;
  const int wl = (wave & 1) * 64, ws = (wave >> 1) * 64;
  f32x4 acc[4][4] = {};
  for (int k = 0; k < 4; ++k) {
    bf16x8 af[4], bfr[4];
    for (int i = 0; i < 4; ++i) {
      int tl = c * 256 + lb + wl + i * 16 + l16;
      af[i] = *(const bf16x8*)(Cmat + (size_t)tl * 128 + k * 32 + quad * 8);
    }
    for (int j = 0; j < 4; ++j) {
      int ts = c * 256 + sb + ws + j * 16 + l16;
      bfr[j] = *(const bf16x8*)(Bmat + (size_t)ts * 128 + k * 32 + quad * 8);
    }
    for (int i = 0; i < 4; ++i)
      for (int j = 0; j < 4; ++j)
        acc[i][j] = __builtin_amdgcn_mfma_f32_16x16x32_bf16(af[i], bfr[j], acc[i][j], 0, 0, 0);
  }
  for (int i = 0; i < 4; ++i)
    for (int j = 0; j < 4; ++j) {
      int lrow = lb + wl + i * 16 + quad * 4;
      int scol = sb + ws + j * 16 + l16;
      for (int r = 0; r < 4; ++r)
        scores[((size_t)c * 256 + lrow + r) * 256 + scol] = (__bf16)acc[i][j][r];
    }
}

// ---------------------------------------------------------------------------
// chunk_states[c][h][p][n] = sum_l xdtT[h,p][l] * (B[l,n] * exp(cs_end - cs_l))
// ---------------------------------------------------------------------------
__global__ __launch_bounds__(256)
void states_kernel(const __bf16* __restrict__ xdtT, const __bf16* __restrict__ BTr,
                   const float* __restrict__ csbuf, __bf16* __restrict__ chunk_states)
{
  const int c = blockIdx.x, h = blockIdx.y;
  const int tid = threadIdx.x, wave = tid >> 6, lane = tid & 63;
  const int quad = lane >> 4, l16 = lane & 15;
  __shared__ float decay[256];
  {
    float cs_end = csbuf[(size_t)h * 4096 + c * 256 + 255];
    decay[tid] = expf(fminf(cs_end - csbuf[(size_t)h * 4096 + c * 256 + tid], 0.f));
  }
  __syncthreads();
  const int wn = wave * 32;
  f32x4 acc[4][2] = {};
  for (int k = 0; k < 8; ++k) {
    bf16x8 af[4], bfr[2];
    for (int i = 0; i < 4; ++i) {
      int p = i * 16 + l16;
      af[i] = *(const bf16x8*)(xdtT + (size_t)(h * 64 + p) * 4096 + c * 256 + k * 32 + quad * 8);
    }
    for (int j = 0; j < 2; ++j) {
      int n = wn + j * 16 + l16;
      bf16x8 raw = *(const bf16x8*)(BTr + (size_t)n * 4096 + c * 256 + k * 32 + quad * 8);
      bf16x8 sc;
      for (int jj = 0; jj < 8; ++jj)
        sc[jj] = (__bf16)((float)raw[jj] * decay[k * 32 + quad * 8 + jj]);
      bfr[j] = sc;
    }
    for (int i = 0; i < 4; ++i)
      for (int j = 0; j < 2; ++j)
        acc[i][j] = __builtin_amdgcn_mfma_f32_16x16x32_bf16(af[i], bfr[j], acc[i][j], 0, 0, 0);
  }
  for (int i = 0; i < 4; ++i)
    for (int j = 0; j < 2; ++j) {
      int p = i * 16 + quad * 4;
      int n = wn + j * 16 + l16;
      for (int r = 0; r < 4; ++r)
        chunk_states[(((size_t)c * 64 + h) * 64 + p + r) * 128 + n] = (__bf16)acc[i][j][r];
    }
}

// ---------------------------------------------------------------------------
// inter-chunk scan, IN-PLACE (states_in[c] overwrites chunk_states[c])
// ---------------------------------------------------------------------------
__global__ __launch_bounds__(256)
void scan_kernel(__bf16* states, const float* __restrict__ csbuf)
{
  size_t id = (size_t)blockIdx.x * 256 + threadIdx.x;  // 64*64*128
  int n = id & 127;
  int p = (int)((id >> 7) & 63);
  int h = (int)(id >> 13);
  float S = 0.f;
  for (int c = 0; c < 16; ++c) {
    size_t idx = (((size_t)c * 64 + h) * 64 + p) * 128 + n;
    float cst = (float)states[idx];
    states[idx] = (__bf16)S;
    float ce = csbuf[(size_t)h * 4096 + c * 256 + 255];
    S = S * expf(fminf(ce, 0.f)) + cst;
  }
}

// ---------------------------------------------------------------------------
// per (chunk, head): Y = exp(cs_l)*(C @ S_in^T) + (scores.decay.mask) @ xdt + x*D
// IN-PLACE: y holds xconv[t][hp] on entry; overwritten with the result.
// ---------------------------------------------------------------------------
__global__ __launch_bounds__(256)
void y_kernel(const __bf16* __restrict__ Cmat, const __bf16* __restrict__ states_in,
              const __bf16* __restrict__ scores, const __bf16* __restrict__ xdtT,
              const float* __restrict__ csbuf, const float* __restrict__ Dvec,
              __bf16* y)
{
  const int c = blockIdx.x, h = blockIdx.y;
  const int tid = threadIdx.x, wave = tid >> 6, lane = tid & 63;
  const int quad = lane >> 4, l16 = lane & 15;
  __shared__ float cs[256];
  cs[tid] = csbuf[(size_t)h * 4096 + c * 256 + tid];
  __syncthreads();
  const int wl = wave * 64;
  f32x4 acc[4][4] = {};

  // Y_off: A = C[l][n], B = states_in[c][h][p][n]
  for (int k = 0; k < 4; ++k) {
    bf16x8 af[4], bfr[4];
    for (int i = 0; i < 4; ++i) {
      int tl = c * 256 + wl + i * 16 + l16;
      af[i] = *(const bf16x8*)(Cmat + (size_t)tl * 128 + k * 32 + quad * 8);
    }
    for (int j = 0; j < 4; ++j) {
      int p = j * 16 + l16;
      bfr[j] = *(const bf16x8*)(states_in + (((size_t)c * 64 + h) * 64 + p) * 128 + k * 32 + quad * 8);
    }
    for (int i = 0; i < 4; ++i)
      for (int j = 0; j < 4; ++j)
        acc[i][j] = __builtin_amdgcn_mfma_f32_16x16x32_bf16(af[i], bfr[j], acc[i][j], 0, 0, 0);
  }
  for (int i = 0; i < 4; ++i)
    for (int r = 0; r < 4; ++r) {
      float sd = expf(fminf(cs[wl + i * 16 + quad * 4 + r], 0.f));
      for (int j = 0; j < 4; ++j) acc[i][j][r] *= sd;
    }
  // Y_diag: A = scores*decay*mask (built per fragment), B = xdtT
  for (int sb = 0; sb < 8; ++sb) {
    bf16x8 af[4], bfr[4];
    for (int i = 0; i < 4; ++i) {
      int lloc = wl + i * 16 + l16;
      bf16x8 raw = *(const bf16x8*)(scores + ((size_t)c * 256 + lloc) * 256 + sb * 32 + quad * 8);
      float csl = cs[lloc];
      bf16x8 w;
      for (int jj = 0; jj < 8; ++jj) {
        int s = sb * 32 + quad * 8 + jj;
        float e = expf(fminf(csl - cs[s], 0.f));
        float v = (s <= lloc) ? (float)raw[jj] * e : 0.f;
        w[jj] = (__bf16)v;
      }
      af[i] = w;
    }
    for (int j = 0; j < 4; ++j) {
      int p = j * 16 + l16;
      bfr[j] = *(const bf16x8*)(xdtT + (size_t)(h * 64 + p) * 4096 + c * 256 + sb * 32 + quad * 8);
    }
    for (int i = 0; i < 4; ++i)
      for (int j = 0; j < 4; ++j)
        acc[i][j] = __builtin_amdgcn_mfma_f32_16x16x32_bf16(af[i], bfr[j], acc[i][j], 0, 0, 0);
  }
  // epilogue: read x (in-place), add x*D, store
  float Dh = Dvec[h];
  for (int i = 0; i < 4; ++i)
    for (int r = 0; r < 4; ++r) {
      int tl = c * 256 + wl + i * 16 + quad * 4 + r;
      for (int j = 0; j < 4; ++j) {
        int p = j * 16 + l16;
        size_t idx = (size_t)tl * 4096 + h * 64 + p;
        float xv = (float)y[idx];
        y[idx] = (__bf16)(acc[i][j][r] + xv * Dh);
      }
    }
}

// ---------------------------------------------------------------------------
extern "C" void kernel_launch(void* const* d_in, const int* in_sizes, int n_in,
                              void* d_out, int out_size, void* d_ws, size_t ws_size,
                              hipStream_t stream)
{
  const float* hs      = (const float*)d_in[0];
  const float* W_in    = (const float*)d_in[1];
  const float* conv_w  = (const float*)d_in[2];
  const float* conv_b  = (const float*)d_in[3];
  const float* dt_bias = (const float*)d_in[4];
  const float* A_log   = (const float*)d_in[5];
  const float* Dv      = (const float*)d_in[6];
  const float* nw      = (const float*)d_in[7];
  const float* W_out   = (const float*)d_in[8];
  float* out = (float*)d_out;

  // Layout, ~94.4 MB. First 16.78MB of d_out doubles as states scratch.
  char* base = (char*)d_ws;
  const size_t P0 = 0;          // 35.65MB: xBCraw -> xdtT -> wTz -> wT_out
  const size_t P1 = 35651584;   // 33.55MB: wTa -> xconv (y, g in-place)
  const size_t P2 = 69206016;   // 8.4MB smalls
  const size_t P3 = 77611008;   // 16.78MB: hs_bf16

  __bf16* xBCraw  = (__bf16*)(base + P0);
  __bf16* xdtT    = (__bf16*)(base + P0);
  __bf16* wTz     = (__bf16*)(base + P0);
  __bf16* wT_out  = (__bf16*)(base + P0);
  __bf16* wTa     = (__bf16*)(base + P1);
  __bf16* xconv   = (__bf16*)(base + P1);
  __bf16* Bmat    = (__bf16*)(base + P2);
  __bf16* Cmat    = (__bf16*)(base + P2 + 1048576);
  __bf16* BTr     = (__bf16*)(base + P2 + 2097152);
  float*  dtp     = (float*) (base + P2 + 3145728);
  float*  csbuf   = (float*) (base + P2 + 4194304);
  __bf16* scores  = (__bf16*)(base + P2 + 5242880);
  float*  dtraw   = (float*) (base + P2 + 7340032);
  float*  ssum    = (float*) (base + P2 + 8388608);   // 16KB
  __bf16* hs16    = (__bf16*)(base + P3);
  __bf16* states  = (__bf16*)d_out;                    // 16.78MB of 33.55MB

  hipMemsetAsync(ssum, 0, 4096 * sizeof(float), stream);
  // 0. cast hs fp32 -> bf16
  cast_kernel<<<4096, 256, 0, stream>>>(hs, hs16);
  // 1. transpose+cast W_in cols [4096,8512) -> wTa[4416][2048]
  transpose_kernel<<<dim3(69, 32), 256, 0, stream>>>(W_in, wTa, 2048, 8512, 4096);
  // 2. GEMM1a: xBC + dtraw
  gemm_kernel<0><<<dim3(35, 32), 256, 0, stream>>>(hs16, wTa, 4096, 4416, 2048, 2048,
                                                   xBCraw, dtraw, nullptr, nullptr, nullptr);
  // 3. conv + SiLU (xconv overwrites wTa)
  conv_silu_kernel<<<8704, 256, 0, stream>>>(xBCraw, conv_w, conv_b, xconv, Bmat, Cmat, BTr);
  // 4. dt softplus + cumsum
  dt_cumsum_kernel<<<dim3(64, 16), 256, 0, stream>>>(dtraw, dt_bias, A_log, dtp, csbuf);
  // 5. xdtT (overwrites dead xBCraw)
  xdtT_kernel<<<dim3(64, 64), 256, 0, stream>>>(xconv, dtp, xdtT);
  // 6. chunk score matrices
  scores_kernel<<<dim3(16, 2, 2), 256, 0, stream>>>(Cmat, Bmat, scores);
  // 7. per-chunk states -> d_out
  states_kernel<<<dim3(16, 64), 256, 0, stream>>>(xdtT, BTr, csbuf, states);
  // 8. inter-chunk scan in-place in d_out
  scan_kernel<<<2048, 256, 0, stream>>>(states, csbuf);
  // 9. y in-place over xconv
  y_kernel<<<dim3(16, 64), 256, 0, stream>>>(Cmat, states, scores, xdtT, csbuf, Dv, xconv);
  // 10. transpose+cast W_in cols [0,4096) -> wTz (xdtT dead)
  transpose_kernel<<<dim3(64, 32), 256, 0, stream>>>(W_in, wTz, 2048, 8512, 0);
  // 11. z-GEMM + gate, in-place on xconv, per-token ssum
  gemm_kernel<2><<<dim3(32, 32), 256, 0, stream>>>(hs16, wTz, 4096, 4096, 2048, 2048,
                                                   nullptr, nullptr, xconv, ssum, nw);
  // 12. transpose+cast W_out -> wT_out (wTz dead)
  transpose_kernel<<<dim3(32, 64), 256, 0, stream>>>(W_out, wT_out, 4096, 2048, 0);
  // 13. GEMM2, no split-K: plain fp32 store, per-row rsqrt scale (states dead)
  gemm_kernel<3><<<dim3(16, 32, 1), 256, 0, stream>>>(xconv, wT_out, 4096, 2048, 4096, 4096,
                                                      nullptr, out, nullptr, ssum, nullptr);
}